// Round 4
// baseline (3427.753 us; speedup 1.0000x reference)
//
#include <hip/hip_runtime.h>
#include <hip/hip_bf16.h>

// RepWalk on MI355X (gfx950). Round 4: runtime input-dtype detection.
// Theory: float inputs are fp32 (reference uses jnp.float32); reading them as
// bf16 u16s produces random-exponent garbage -> inf -> NaN (matches rounds 1-3).
// A detect kernel sets flag (0=bf16, 1=fp32); all input reads go through a
// dual-dtype helper. GEMMs use hi+lo bf16 splitting on BOTH operands (3 MFMA
// passes) for fp32-level accuracy. Recurrence weights kept fp32.
// Output written fp32 if flag=1 else bf16.

typedef unsigned short u16;
typedef __attribute__((ext_vector_type(8))) short short8;
typedef __attribute__((ext_vector_type(4))) float floatx4;

#define NEGV -1e9f

__device__ __forceinline__ float bf2f(u16 u) {
    union { unsigned int i; float f; } x; x.i = ((unsigned int)u) << 16; return x.f;
}
__device__ __forceinline__ u16 f2bf(float f) {
    unsigned int u = __float_as_uint(f);
    unsigned int r = (u + 0x7fff + ((u >> 16) & 1)) >> 16;
    return (u16)r;
}
__device__ __forceinline__ float sigm(float x) { return 1.f / (1.f + expf(-x)); }
// dual-dtype read of logical element i of a float tensor
__device__ __forceinline__ float rdf(const void* p, size_t i, int flag) {
    return flag ? ((const float*)p)[i] : bf2f(((const u16*)p)[i]);
}

// ---------------- dtype detect ----------------
// Scan u16 elements [4096,4352) of emb (nonzero normal data in either dtype).
// fp32 data: even u16s are mantissa bits -> ~46% have bf16 exponent >= 0x8A.
__global__ void k_detect(const void* __restrict__ emb, int* __restrict__ flag) {
    __shared__ int cnt;
    if (threadIdx.x == 0) cnt = 0;
    __syncthreads();
    u16 x = ((const u16*)emb)[4096 + threadIdx.x];
    int e = (x >> 7) & 0xFF;
    if (e >= 0x8A) atomicAdd(&cnt, 1);
    __syncthreads();
    if (threadIdx.x == 0) *flag = (cnt > 8) ? 1 : 0;
}

// ---------------- small prep kernels ----------------

__global__ void k_prep_small(const int* __restrict__ text, const int* __restrict__ asp,
                             int* __restrict__ lens) {
    int tid = threadIdx.x;
    if (tid < 64) {
        int c = 0;
        for (int s = 0; s < 128; ++s) c += (text[tid * 128 + s] != 0);
        lens[tid] = c;
    } else if (tid < 128) {
        int b = tid - 64; int c = 0;
        for (int a = 0; a < 8; ++a) c += (asp[b * 8 + a] != 0);
        lens[64 + b] = c;
    }
}

// gather embeddings for positions [base, base+csteps) -> hi/lo bf16, K pad 320
__global__ void k_embed_pos(const void* __restrict__ emb, const int* __restrict__ ids,
                            int base, int csteps, int stride, const int* __restrict__ flag,
                            u16* __restrict__ dhi, u16* __restrict__ dlo) {
    int i = blockIdx.x * 256 + threadIdx.x;
    if (i >= 64 * csteps * 320) return;
    int f = *flag;
    int r = i / 320, k = i - r * 320;
    int b = r / csteps, j = r - b * csteps;
    int id = ids[b * stride + base + j];
    float val = (k < 300) ? rdf(emb, (size_t)id * 300 + k, f) : 0.f;
    u16 hi = f2bf(val);
    dhi[i] = hi;
    dlo[i] = f2bf(val - bf2f(hi));
}

// Wih [2,1200,300] -> padded [2432,320] hi/lo
__global__ void k_pad_wih(const void* __restrict__ W, const int* __restrict__ flag,
                          u16* __restrict__ dhi, u16* __restrict__ dlo) {
    int i = blockIdx.x * 256 + threadIdx.x;
    if (i >= 2432 * 320) return;
    int f = *flag;
    int n = i / 320, k = i - n * 320;
    float val = (n < 2400 && k < 300) ? rdf(W, (size_t)n * 300 + k, f) : 0.f;
    u16 hi = f2bf(val);
    dhi[i] = hi;
    dlo[i] = f2bf(val - bf2f(hi));
}

// Whh [2,1200,300] -> WhhT fp32 [2,300,1200]
__global__ void k_whhT(const void* __restrict__ W, const int* __restrict__ flag,
                       float* __restrict__ dst) {
    int i = blockIdx.x * 256 + threadIdx.x;
    if (i >= 720000) return;
    int f = *flag;
    int dir = i / 360000, r = i - dir * 360000;
    int k = r / 1200, g = r - k * 1200;
    dst[i] = rdf(W, (size_t)dir * 360000 + (size_t)g * 300 + k, f);
}

// lin1_W [2,600,1200] -> padded [2,640,1216] hi/lo
__global__ void k_pad_lin1(const void* __restrict__ W, const int* __restrict__ flag,
                           u16* __restrict__ dhi, u16* __restrict__ dlo) {
    int i = blockIdx.x * 256 + threadIdx.x;
    if (i >= 2 * 640 * 1216) return;
    int f = *flag;
    int dir = i / (640 * 1216), r = i - dir * (640 * 1216);
    int n = r / 1216, k = r - n * 1216;
    float val = (n < 600 && k < 1200)
        ? rdf(W, (size_t)dir * 720000 + (size_t)n * 1200 + k, f) : 0.f;
    u16 hi = f2bf(val);
    dhi[i] = hi;
    dlo[i] = f2bf(val - bf2f(hi));
}

__global__ void k_bias(const void* b1i, const void* b1h, const void* b2i, const void* b2h,
                       const void* lb, const int* __restrict__ flag,
                       float* bt, float* ba, float* bl) {
    int i = blockIdx.x * 256 + threadIdx.x;
    int f = *flag;
    if (i < 2400) {
        bt[i] = rdf(b1i, i, f) + rdf(b1h, i, f);
        ba[i] = rdf(b2i, i, f) + rdf(b2h, i, f);
    }
    if (i < 1280) {
        int dir = i / 640, c = i - dir * 640;
        bl[i] = (c < 600) ? rdf(lb, dir * 600 + c, f) : 0.f;
    }
}

// convert small tensors (pw 8192, lin2_W 1200, lin2_b 2, fcW 1800, fcb 3) -> fp32
__global__ void k_cvt(const void* pw, const void* l2w, const void* l2b,
                      const void* fcw, const void* fcb, const int* __restrict__ flag,
                      float* __restrict__ dst) {
    int i = blockIdx.x * 256 + threadIdx.x;
    int f = *flag;
    if (i < 8192)            dst[i] = rdf(pw, i, f);
    else if (i < 9392)       dst[i] = rdf(l2w, i - 8192, f);
    else if (i < 9394)       dst[i] = rdf(l2b, i - 9392, f);
    else if (i < 11194)      dst[i] = rdf(fcw, i - 9394, f);
    else if (i < 11197)      dst[i] = rdf(fcb, i - 11194, f);
}

// ---------------- MFMA GEMM: C = (Ahi+Alo)[M,K] @ (Bhi+Blo)[N,K]^T ----------------
// 3 passes: Ahi*Bhi + Ahi*Blo + Alo*Bhi (Alo*Blo negligible).
// mode 0: C = acc + bias ; mode 1: fused lin1 epilogue into vio at row+mrowoff

__global__ __launch_bounds__(256) void gemm_bt(
    const u16* __restrict__ Ahi, const u16* __restrict__ Alo, int lda,
    const u16* __restrict__ Bhi, const u16* __restrict__ Blo, int ldb,
    const float* __restrict__ bias,
    float* __restrict__ C, int ldc, int nstore, int K, int mode,
    const float* __restrict__ tg, const float* __restrict__ pw, float* __restrict__ vio,
    int mrowoff)
{
    int tid = threadIdx.x;
    int wave = tid >> 6, lane = tid & 63;
    int l15 = lane & 15, quad = lane >> 4;
    int m0 = blockIdx.x * 64 + wave * 16;
    int n0 = blockIdx.y * 64;

    const u16* Ap  = Ahi + (size_t)(m0 + l15) * lda + quad * 8;
    const u16* Ap2 = Alo + (size_t)(m0 + l15) * lda + quad * 8;
    const u16* Bp  = Bhi + (size_t)(n0 + l15) * ldb + quad * 8;
    const u16* Bp2 = Blo + (size_t)(n0 + l15) * ldb + quad * 8;

    floatx4 acc0 = {0.f, 0.f, 0.f, 0.f};
    floatx4 acc1 = acc0, acc2 = acc0, acc3 = acc0;

    int nk = K >> 5;
    for (int kc = 0; kc < nk; ++kc) {
        int ko = kc * 32;
        short8 bh0 = *(const short8*)(Bp + ko);
        short8 bh1 = *(const short8*)(Bp + (size_t)16 * ldb + ko);
        short8 bh2 = *(const short8*)(Bp + (size_t)32 * ldb + ko);
        short8 bh3 = *(const short8*)(Bp + (size_t)48 * ldb + ko);
        short8 bl0 = *(const short8*)(Bp2 + ko);
        short8 bl1 = *(const short8*)(Bp2 + (size_t)16 * ldb + ko);
        short8 bl2 = *(const short8*)(Bp2 + (size_t)32 * ldb + ko);
        short8 bl3 = *(const short8*)(Bp2 + (size_t)48 * ldb + ko);
        short8 a  = *(const short8*)(Ap + ko);
        short8 al = *(const short8*)(Ap2 + ko);
        acc0 = __builtin_amdgcn_mfma_f32_16x16x32_bf16(a, bh0, acc0, 0, 0, 0);
        acc1 = __builtin_amdgcn_mfma_f32_16x16x32_bf16(a, bh1, acc1, 0, 0, 0);
        acc2 = __builtin_amdgcn_mfma_f32_16x16x32_bf16(a, bh2, acc2, 0, 0, 0);
        acc3 = __builtin_amdgcn_mfma_f32_16x16x32_bf16(a, bh3, acc3, 0, 0, 0);
        acc0 = __builtin_amdgcn_mfma_f32_16x16x32_bf16(a, bl0, acc0, 0, 0, 0);
        acc1 = __builtin_amdgcn_mfma_f32_16x16x32_bf16(a, bl1, acc1, 0, 0, 0);
        acc2 = __builtin_amdgcn_mfma_f32_16x16x32_bf16(a, bl2, acc2, 0, 0, 0);
        acc3 = __builtin_amdgcn_mfma_f32_16x16x32_bf16(a, bl3, acc3, 0, 0, 0);
        acc0 = __builtin_amdgcn_mfma_f32_16x16x32_bf16(al, bh0, acc0, 0, 0, 0);
        acc1 = __builtin_amdgcn_mfma_f32_16x16x32_bf16(al, bh1, acc1, 0, 0, 0);
        acc2 = __builtin_amdgcn_mfma_f32_16x16x32_bf16(al, bh2, acc2, 0, 0, 0);
        acc3 = __builtin_amdgcn_mfma_f32_16x16x32_bf16(al, bh3, acc3, 0, 0, 0);
    }

    #pragma unroll
    for (int c = 0; c < 4; ++c) {
        floatx4 acc = (c == 0) ? acc0 : (c == 1) ? acc1 : (c == 2) ? acc2 : acc3;
        int col = n0 + c * 16 + l15;
        if (col >= nstore) continue;
        float bb = bias[col];
        #pragma unroll
        for (int r = 0; r < 4; ++r) {
            int row = m0 + quad * 4 + r;
            float val = acc[r] + bb;
            if (mode == 1) {
                val = val > 0.f ? val : 0.01f * val;     // leaky_relu slope 0.01
                int rg = row + mrowoff;
                float t = tg[rg];
                size_t vi = (size_t)rg * 600 + col;
                float vv = vio[vi];
                vio[vi] = pw[rg] * ((1.f - t) * val + t * vv);
            } else {
                C[(size_t)row * ldc + col] = val;
            }
        }
    }
}

// ---------------- LSTM recurrence (chunked): one block per (b, dir) ----------------
// WhhT fp32 [2,300,1200]; xf/xb rows: b*rpb + (pos - base); state in hst/cst.

__global__ __launch_bounds__(320) void k_lstm(
    const float* __restrict__ xf, const float* __restrict__ xb, int ldx, int rpb,
    int base_f, int base_b, const float* __restrict__ whhT,
    const int* __restrict__ lens, float* __restrict__ out, int T, int init,
    float* __restrict__ hst, float* __restrict__ cst, int nsteps)
{
    int b = blockIdx.x >> 1, dir = blockIdx.x & 1;
    int chain = blockIdx.x;
    int len = lens[b];
    int tid = threadIdx.x;
    __shared__ float h_s[300];
    __shared__ float g_s[1200];
    float c = 0.f;
    if (tid < 300) {
        h_s[tid] = init ? 0.f : hst[(size_t)chain * 300 + tid];
        c = init ? 0.f : cst[(size_t)chain * 300 + tid];
    }
    __syncthreads();
    const float* wb = whhT + (size_t)dir * 360000;
    const float4* wbase4 = (const float4*)wb + tid;   // gate cols 4t..4t+3

    for (int j = 0; j < nsteps; ++j) {
        int pos = dir ? (base_b + nsteps - 1 - j) : (base_f + j);
        if (pos >= len) continue;          // uniform per block (len per b)
        const float* xr = dir ? (xb + (size_t)(b * rpb + pos - base_b) * ldx)
                              : (xf + (size_t)(b * rpb + pos - base_f) * ldx);
        if (tid < 300) {
            float4 xa = *(const float4*)(xr + 4 * tid);
            float a0 = xa.x, a1 = xa.y, a2 = xa.z, a3 = xa.w;
            #pragma unroll 4
            for (int k = 0; k < 300; ++k) {
                float hk = h_s[k];
                float4 wv = wbase4[(size_t)k * 300];
                a0 = fmaf(hk, wv.x, a0);
                a1 = fmaf(hk, wv.y, a1);
                a2 = fmaf(hk, wv.z, a2);
                a3 = fmaf(hk, wv.w, a3);
            }
            g_s[4 * tid + 0] = a0; g_s[4 * tid + 1] = a1;
            g_s[4 * tid + 2] = a2; g_s[4 * tid + 3] = a3;
        }
        __syncthreads();
        if (tid < 300) {
            float gi = sigm(g_s[tid]);
            float gf = sigm(g_s[300 + tid]);
            float gg = tanhf(g_s[600 + tid]);
            float go = sigm(g_s[900 + tid]);
            c = gf * c + gi * gg;
            float hn = go * tanhf(c);
            out[(size_t)(b * T + pos) * 600 + dir * 300 + tid] = hn;
            h_s[tid] = hn;
        }
        __syncthreads();
    }
    if (tid < 300) {
        hst[(size_t)chain * 300 + tid] = h_s[tid];
        cst[(size_t)chain * 300 + tid] = c;
    }
}

// ---------------- attention iteration kernels ----------------

__global__ __launch_bounds__(64) void k_scores(
    const float* __restrict__ v, const float* __restrict__ e,
    const int* __restrict__ text, const int* __restrict__ asp,
    const float* __restrict__ l2w, const float* __restrict__ l2b, int iter,
    float* __restrict__ a_sm, float* __restrict__ tg)
{
    int row = blockIdx.x, b = row >> 7, lane = threadIdx.x;
    float acc[9];
    #pragma unroll
    for (int j = 0; j < 9; ++j) acc[j] = 0.f;
    const float* vrow = v + (size_t)row * 600;
    const float* eb = e + (size_t)b * 4800;
    const float* w2 = l2w + iter * 600;
    for (int d = lane; d < 600; d += 64) {
        float vv = vrow[d];
        #pragma unroll
        for (int a = 0; a < 8; ++a) acc[a] += vv * eb[a * 600 + d];
        acc[8] += vv * w2[d];
    }
    #pragma unroll
    for (int off = 32; off >= 1; off >>= 1) {
        #pragma unroll
        for (int j = 0; j < 9; ++j) acc[j] += __shfl_down(acc[j], off, 64);
    }
    if (lane == 0) {
        tg[row] = sigm(acc[8] + l2b[iter]);
        bool sm = (text[row] != 0);
        float sc[8]; float mx = -INFINITY;
        #pragma unroll
        for (int a = 0; a < 8; ++a) {
            sc[a] = (sm && asp[b * 8 + a] != 0) ? acc[a] : NEGV;
            mx = fmaxf(mx, sc[a]);
        }
        float den = 0.f;
        #pragma unroll
        for (int a = 0; a < 8; ++a) { sc[a] = expf(sc[a] - mx); den += sc[a]; }
        float inv = 1.f / den;
        #pragma unroll
        for (int a = 0; a < 8; ++a) a_sm[(size_t)row * 8 + a] = sc[a] * inv;
    }
}

// build cat = [mid, v] (bf16 hi + lo), rows [rowoff, rowoff+2048), K pad 1216
__global__ void k_midcat(const float* __restrict__ a_sm, const float* __restrict__ e,
                         const float* __restrict__ v, int rowoff,
                         u16* __restrict__ cat_hi, u16* __restrict__ cat_lo)
{
    int d = blockIdx.x * 256 + threadIdx.x;
    int rl = blockIdx.y;
    if (d >= 1216) return;
    int row = rowoff + rl;
    int b = row >> 7;
    float val;
    if (d < 600) {
        const float* as = a_sm + (size_t)row * 8;
        const float* eb = e + (size_t)b * 4800 + d;
        float m = 0.f;
        #pragma unroll
        for (int a = 0; a < 8; ++a) m += as[a] * eb[a * 600];
        val = m;
    } else if (d < 1200) {
        val = v[(size_t)row * 600 + (d - 600)];
    } else {
        val = 0.f;
    }
    u16 hi = f2bf(val);
    cat_hi[(size_t)rl * 1216 + d] = hi;
    cat_lo[(size_t)rl * 1216 + d] = f2bf(val - bf2f(hi));
}

// ---------------- final kernels ----------------

__global__ void k_query(const float* __restrict__ e, const int* __restrict__ asp,
                        float* __restrict__ q) {
    int i = blockIdx.x * 256 + threadIdx.x;
    if (i >= 64 * 600) return;
    int b = i / 600, d = i - b * 600;
    float m = NEGV;
    for (int a = 0; a < 8; ++a)
        if (asp[b * 8 + a] != 0) m = fmaxf(m, e[(size_t)b * 4800 + a * 600 + d]);
    q[i] = m;
}

__global__ __launch_bounds__(128) void k_final(
    const float* __restrict__ v, const float* __restrict__ q,
    const int* __restrict__ text, const float* __restrict__ fcW,
    const float* __restrict__ fcb, const int* __restrict__ flag, void* __restrict__ outv)
{
    __shared__ float red[128];
    __shared__ float al[128];
    __shared__ float zz[600];
    int b = blockIdx.x, s = threadIdx.x;
    const float* vrow = v + (size_t)(b * 128 + s) * 600;
    const float* qb = q + (size_t)b * 600;
    float sc = 0.f;
    for (int d = 0; d < 600; ++d) sc += vrow[d] * qb[d];
    if (text[b * 128 + s] == 0) sc = NEGV;
    red[s] = sc; __syncthreads();
    for (int off = 64; off >= 1; off >>= 1) {
        if (s < off) red[s] = fmaxf(red[s], red[s + off]);
        __syncthreads();
    }
    float mx = red[0]; __syncthreads();
    float ex = expf(sc - mx);
    red[s] = ex; __syncthreads();
    for (int off = 64; off >= 1; off >>= 1) {
        if (s < off) red[s] += red[s + off];
        __syncthreads();
    }
    float alpha = ex / red[0];
    al[s] = alpha; __syncthreads();
    for (int d = s; d < 600; d += 128) {
        float z = 0.f;
        for (int s2 = 0; s2 < 128; ++s2) z += al[s2] * v[(size_t)(b * 128 + s2) * 600 + d];
        zz[d] = z;
    }
    __syncthreads();
    if (s < 3) {
        float o = 0.f;
        for (int d = 0; d < 600; ++d) o += zz[d] * fcW[s * 600 + d];
        o += fcb[s];
        if (*flag) ((float*)outv)[b * 3 + s] = o;
        else       ((u16*)outv)[b * 3 + s] = f2bf(o);
    }
}

// ---------------- host launch ----------------

extern "C" void kernel_launch(void* const* d_in, const int* in_sizes, int n_in,
                              void* d_out, int out_size, void* d_ws, size_t ws_size,
                              hipStream_t stream) {
    const int*  text   = (const int*)d_in[0];
    const int*  asp    = (const int*)d_in[1];
    const void* pw     = d_in[2];
    const void* emb    = d_in[3];
    const void* l1_Wih = d_in[4];
    const void* l1_Whh = d_in[5];
    const void* l1_bih = d_in[6];
    const void* l1_bhh = d_in[7];
    const void* l2_Wih = d_in[8];
    const void* l2_Whh = d_in[9];
    const void* l2_bih = d_in[10];
    const void* l2_bhh = d_in[11];
    const void* lin1_W = d_in[12];
    const void* lin1_b = d_in[13];
    const void* lin2_W = d_in[14];
    const void* lin2_b = d_in[15];
    const void* fcW    = d_in[16];
    const void* fcb    = d_in[17];
    (void)ws_size; (void)n_in; (void)in_sizes; (void)out_size;

    char* w = (char*)d_ws;
    size_t off = 0;
    auto alloc = [&](size_t bytes) -> void* {
        void* p = w + off;
        off += (bytes + 255) & ~(size_t)255;
        return p;
    };
    // ---- persistent (~22.1 MB) ----
    int*   flag    = (int*)  alloc(4);
    int*   lens    = (int*)  alloc(128ull * 4);
    float* bias_t  = (float*)alloc(2400ull * 4);
    float* bias_a  = (float*)alloc(2400ull * 4);
    float* bias_l1 = (float*)alloc(1280ull * 4);
    float* smallf  = (float*)alloc(11197ull * 4);   // pw|l2w|l2b|fcW|fcb
    float* tg      = (float*)alloc(8192ull * 4);
    float* a_sm    = (float*)alloc(8192ull * 8 * 4);
    float* query   = (float*)alloc(64ull * 600 * 4);
    float* hst_t   = (float*)alloc(128ull * 300 * 4);
    float* cst_t   = (float*)alloc(128ull * 300 * 4);
    float* hst_a   = (float*)alloc(128ull * 300 * 4);
    float* cst_a   = (float*)alloc(128ull * 300 * 4);
    float* e       = (float*)alloc(512ull * 600 * 4);
    float* v       = (float*)alloc(8192ull * 600 * 4);
    float* pw_f    = smallf;
    float* l2w_f   = smallf + 8192;
    float* l2b_f   = smallf + 9392;
    float* fcW_f   = smallf + 9394;
    float* fcb_f   = smallf + 11194;
    // ---- phase region: union of A and B (~25 MB) ----
    size_t phase_off = off;
    // phase A (LSTM phase)
    u16*   wfcf_hi  = (u16*)  alloc(1024ull * 320 * 2);
    u16*   wfcf_lo  = (u16*)  alloc(1024ull * 320 * 2);
    u16*   wfcb_hi  = (u16*)  alloc(1024ull * 320 * 2);
    u16*   wfcb_lo  = (u16*)  alloc(1024ull * 320 * 2);
    u16*   af_hi    = (u16*)  alloc(512ull * 320 * 2);
    u16*   af_lo    = (u16*)  alloc(512ull * 320 * 2);
    u16*   wiht_hi  = (u16*)  alloc(2432ull * 320 * 2);
    u16*   wiht_lo  = (u16*)  alloc(2432ull * 320 * 2);
    u16*   wiha_hi  = (u16*)  alloc(2432ull * 320 * 2);
    u16*   wiha_lo  = (u16*)  alloc(2432ull * 320 * 2);
    float* whhT_t   = (float*)alloc(720000ull * 4);
    float* whhT_a   = (float*)alloc(720000ull * 4);
    float* xf       = (float*)alloc(1024ull * 1200 * 4);   // == 512*2400*4 (xproj_a alias)
    float* xb       = (float*)alloc(1024ull * 1200 * 4);
    float* xproj_a  = xf;
    // phase B (attention) aliases phase A
    off = phase_off;
    u16*   l1w_hi   = (u16*)  alloc(2ull * 640 * 1216 * 2);
    u16*   l1w_lo   = (u16*)  alloc(2ull * 640 * 1216 * 2);
    u16*   cat_hi   = (u16*)  alloc(2048ull * 1216 * 2);
    u16*   cat_lo   = (u16*)  alloc(2048ull * 1216 * 2);

    hipMemsetAsync(v, 0, 8192ull * 600 * 4, stream);
    hipMemsetAsync(e, 0, 512ull * 600 * 4, stream);

    // ---- prep ----
    k_detect<<<1, 256, 0, stream>>>(emb, flag);
    k_prep_small<<<1, 128, 0, stream>>>(text, asp, lens);
    k_pad_wih<<<(2432 * 320 + 255) / 256, 256, 0, stream>>>(l1_Wih, flag, wiht_hi, wiht_lo);
    k_pad_wih<<<(2432 * 320 + 255) / 256, 256, 0, stream>>>(l2_Wih, flag, wiha_hi, wiha_lo);
    k_whhT<<<(720000 + 255) / 256, 256, 0, stream>>>(l1_Whh, flag, whhT_t);
    k_whhT<<<(720000 + 255) / 256, 256, 0, stream>>>(l2_Whh, flag, whhT_a);
    k_bias<<<10, 256, 0, stream>>>(l1_bih, l1_bhh, l2_bih, l2_bhh, lin1_b, flag,
                                   bias_t, bias_a, bias_l1);
    k_cvt<<<44, 256, 0, stream>>>(pw, lin2_W, lin2_b, fcW, fcb, flag, smallf);

    // ---- aspect path (xproj_a aliases xf; completes before text chunks) ----
    k_embed_pos<<<(512 * 320 + 255) / 256, 256, 0, stream>>>(emb, asp, 0, 8, 8, flag,
                                                             af_hi, af_lo);
    gemm_bt<<<dim3(8, 38), 256, 0, stream>>>(af_hi, af_lo, 320, wiha_hi, wiha_lo, 320,
        bias_a, xproj_a, 2400, 2400, 320, 0, nullptr, nullptr, nullptr, 0);
    k_lstm<<<128, 320, 0, stream>>>(xproj_a, xproj_a + 1200, 2400, 8, 0, 0,
        whhT_a, lens + 64, e, 8, 1, hst_a, cst_a, 8);

    // ---- text path: 8 chunks of 16 steps ----
    for (int k = 0; k < 8; ++k) {
        int bf = 16 * k;          // fwd base
        int bb = 112 - 16 * k;    // bwd base (descending consumption)
        k_embed_pos<<<(1024 * 320 + 255) / 256, 256, 0, stream>>>(emb, text, bf, 16, 128,
                                                                  flag, wfcf_hi, wfcf_lo);
        k_embed_pos<<<(1024 * 320 + 255) / 256, 256, 0, stream>>>(emb, text, bb, 16, 128,
                                                                  flag, wfcb_hi, wfcb_lo);
        gemm_bt<<<dim3(16, 19), 256, 0, stream>>>(wfcf_hi, wfcf_lo, 320,
            wiht_hi, wiht_lo, 320, bias_t, xf, 1200, 1200, 320, 0,
            nullptr, nullptr, nullptr, 0);
        gemm_bt<<<dim3(16, 19), 256, 0, stream>>>(wfcb_hi, wfcb_lo, 320,
            wiht_hi + 1200ull * 320, wiht_lo + 1200ull * 320, 320, bias_t + 1200,
            xb, 1200, 1200, 320, 0, nullptr, nullptr, nullptr, 0);
        k_lstm<<<128, 320, 0, stream>>>(xf, xb, 1200, 16, bf, bb,
            whhT_t, lens, v, 128, k == 0 ? 1 : 0, hst_t, cst_t, 16);
    }

    // ---- phase B prep (after all phase-A consumers in stream order) ----
    k_pad_lin1<<<(2 * 640 * 1216 + 255) / 256, 256, 0, stream>>>(lin1_W, flag,
                                                                 l1w_hi, l1w_lo);

    // ---- two attention iterations, GEMM chunked by 2048 rows ----
    for (int iter = 0; iter < 2; ++iter) {
        k_scores<<<8192, 64, 0, stream>>>(v, e, text, asp, l2w_f, l2b_f, iter, a_sm, tg);
        for (int c = 0; c < 4; ++c) {
            int rowoff = c * 2048;
            k_midcat<<<dim3(5, 2048), 256, 0, stream>>>(a_sm, e, v, rowoff, cat_hi, cat_lo);
            gemm_bt<<<dim3(32, 10), 256, 0, stream>>>(cat_hi, cat_lo, 1216,
                l1w_hi + (size_t)iter * 640 * 1216, l1w_lo + (size_t)iter * 640 * 1216,
                1216, bias_l1 + iter * 640,
                nullptr, 0, 600, 1216, 1, tg, pw_f, v, rowoff);
        }
    }

    // ---- final ----
    k_query<<<150, 256, 0, stream>>>(e, asp, query);
    k_final<<<64, 128, 0, stream>>>(v, query, text, fcW_f, fcb_f, flag, d_out);
}